// Round 3
// baseline (120.150 us; speedup 1.0000x reference)
//
#include <hip/hip_runtime.h>
#include <hip/hip_bf16.h>
#include <math.h>

#define KK 5
#define KN 32
#define CIN 16
#define H 64
#define W 64
#define NB 32
#define HO 60
#define WO 60
#define D_TOT 400
#define OUT_PLANE (NB*HO*WO*KN)

// block tile: 4 out-rows x 16 out-cols, 4 waves, one row per wave
#define TH 4
#define TW 16
#define IN_R 8       // TH + KK - 1
#define IN_C 20      // TW + KK - 1
#define CPAD 24      // c padded 16 -> 24 shorts (48B col stride: 2-way banks, free)
#define TILE_SH (IN_R*IN_C*CPAD)   // 3840 shorts per map
#define NKSTEP 13                  // ceil(400/32)

typedef short short8 __attribute__((ext_vector_type(8)));
typedef float f32x4 __attribute__((ext_vector_type(4)));

__device__ __forceinline__ ushort f2bf(float x) {
    __hip_bfloat16 h = __float2bfloat16(x);
    return *reinterpret_cast<ushort*>(&h);
}
__device__ __forceinline__ float bf2f(ushort u) {
    __hip_bfloat16 h = *reinterpret_cast<__hip_bfloat16*>(&u);
    return __bfloat162float(h);
}
__device__ __forceinline__ ushort4 pk4(float4 v) {
    union { __hip_bfloat162 h; ushort2 u; } a, b;
    a.h = __float22bfloat162_rn(make_float2(v.x, v.y));
    b.h = __float22bfloat162_rn(make_float2(v.z, v.w));
    ushort4 r;
    r.x = a.u.x; r.y = a.u.y; r.z = b.u.x; r.w = b.u.y;
    return r;
}
__device__ __forceinline__ float softplusf(float x) {
    return (x > 20.0f) ? x : __logf(1.0f + __expf(x));
}

// ---------------- prep: pack B fragments + spw + KL ----------------
// Bpack layout (short8 frags): idx8 = (t*2 + nt)*64 + lane ; element j:
//   k = t*32 + ((lane>>4)&3)*8 + j ; n = nt*16 + (lane&15); zero for k>=400
__global__ void prep_all(const float* __restrict__ w_mu, const float* __restrict__ w_sigma,
                         ushort* __restrict__ bmu, ushort* __restrict__ bsq,
                         float* __restrict__ spw, float* __restrict__ kl_out) {
    __shared__ float red[256];
    int t = threadIdx.x;
    if (blockIdx.x < 52) {
        int idx = blockIdx.x * 256 + t;     // < 13312
        int j  = idx & 7;
        int l  = (idx >> 3) & 63;
        int nt = (idx >> 9) & 1;
        int ts = idx >> 10;
        int k  = ts * 32 + ((l >> 4) & 3) * 8 + j;
        int n  = nt * 16 + (l & 15);
        float w = (k < D_TOT) ? w_mu[k * KN + n] : 0.0f;
        bmu[idx] = f2bf(w);
        bsq[idx] = f2bf(w * w * (1.0f / 400.0f));
    } else {
        float s = 0.f;
        for (int i = t; i < D_TOT * KN; i += 256) { float w = w_mu[i]; s += w * w; }
        red[t] = s;
        __syncthreads();
        for (int off = 128; off > 0; off >>= 1) {
            if (t < off) red[t] += red[t + off];
            __syncthreads();
        }
        float sum_w2 = red[0];
        if (t < KN) {
            float ws = w_sigma[t];
            spw[t] = log1pf(expf(ws)) * (1.0f / 400.0f);
        }
        if (t == 0) {
            float sws = 0.f;
            for (int kn = 0; kn < KN; ++kn) {
                float ws = w_sigma[kn];
                float sp = log1pf(expf(ws));
                sws += -ws + sp * 100.0f;
            }
            float kl = 0.5f * (-4.605170186f - 1.0f + sws * (1.0f / 32.0f)
                               + sum_w2 * (100.0f / 12800.0f));
            *kl_out = kl;
        }
    }
}

// ---------------- main ----------------
__global__ __launch_bounds__(256, 5)
void vdp_main(const float* __restrict__ mu_in, const float* __restrict__ sig_in,
              const ushort* __restrict__ bmu_g, const ushort* __restrict__ bsq_g,
              const float* __restrict__ spw,
              float* __restrict__ mu_out, float* __restrict__ sig_out) {
    __shared__ ushort tiles[2 * TILE_SH + 8];
    __shared__ float csum[IN_R * IN_C];   // per input pixel: sum_c (sigma + mu^2)
    __shared__ float t12s[TH * TW];

    const int b   = blockIdx.z;
    const int ho0 = blockIdx.y * TH;
    const int wo0 = blockIdx.x * TW;
    const int t   = threadIdx.x;

    if (t < 8) tiles[2 * TILE_SH + t] = 0;   // zero pad for k>=400 A reads

    // ---- stage 8x20x16 fp32 -> bf16 LDS (c-padded to 24) ----
    // ho0+row <= 56+7 = 63 < H always; only gw needs a guard.
    for (int i = t; i < IN_R * IN_C * 4; i += 256) {   // 640 float4 per map
        int row = i / 80;
        int rem = i - row * 80;
        int col = rem >> 2, c4 = rem & 3;
        int gw = wo0 + col;
        float4 vm = make_float4(0.f, 0.f, 0.f, 0.f), vs = vm;
        if (gw < W) {
            size_t g = (((size_t)b * H + ho0 + row) * W + gw) * CIN + c4 * 4;
            vm = *(const float4*)(mu_in + g);
            vs = *(const float4*)(sig_in + g);
        }
        int sb = (row * IN_C + col) * CPAD + c4 * 4;
        *(ushort4*)&tiles[sb] = pk4(vm);
        *(ushort4*)&tiles[TILE_SH + sb] = pk4(vs);
    }
    __syncthreads();

    // ---- per-input-pixel channel sums: csum = sum_c(sigma + mu^2) ----
    if (t < IN_R * IN_C) {
        int sb = t * CPAD;
        float acc = 0.f;
#pragma unroll
        for (int g = 0; g < 4; ++g) {
            ushort4 m4 = *(ushort4*)&tiles[sb + g * 4];
            ushort4 s4 = *(ushort4*)&tiles[TILE_SH + sb + g * 4];
            float m0 = bf2f(m4.x), m1 = bf2f(m4.y), m2 = bf2f(m4.z), m3 = bf2f(m4.w);
            acc += bf2f(s4.x) + bf2f(s4.y) + bf2f(s4.z) + bf2f(s4.w);
            acc += m0 * m0 + m1 * m1 + m2 * m2 + m3 * m3;
        }
        csum[t] = acc;
    }
    __syncthreads();

    // ---- 5x5 window sums: t12 per output pixel ----
    if (t < TH * TW) {
        int r = t >> 4, c = t & 15;
        float s = 0.f;
#pragma unroll
        for (int kh = 0; kh < KK; ++kh)
#pragma unroll
            for (int kw = 0; kw < KK; ++kw)
                s += csum[(r + kh) * IN_C + c + kw];
        t12s[t] = s;
    }
    __syncthreads();

    // ---- MFMA k-loop: wave w computes output row w of the tile ----
    const int w    = t >> 6;
    const int l    = t & 63;
    const int col  = l & 15;        // output pixel column (A-matrix m index)
    const int q    = l >> 4;
    const int qh   = q >> 1;        // which (kh,kw) position within kstep pair
    const int qc   = q & 1;         // which c-half

    const char* lds = (const char*)tiles;
    const int base  = (w * IN_C + col) * (CPAD * 2) + qc * 16;  // bytes
    const int qh48  = qh * 48;
    const int qh768 = qh * 768;
    const int zpad  = 2 * TILE_SH * 2;   // byte offset of zero pad
    const int SGOFF = TILE_SH * 2;       // byte offset of sigma map

    const short8* Bmu8 = (const short8*)bmu_g;
    const short8* Bsq8 = (const short8*)bsq_g;

    f32x4 accm[2], accs[2];
    f32x4 z = {0.f, 0.f, 0.f, 0.f};
    accm[0] = z; accm[1] = z; accs[0] = z; accs[1] = z;

    // F0v = kh*20+kw spatial offset of even position; D16 flags row-crossing pairs
    constexpr int F0v[NKSTEP] = {0, 2, 4, 21, 23, 40, 42, 44, 61, 63, 80, 82, 84};
    constexpr int D16[NKSTEP] = {0, 0, 1, 0, 0, 0, 0, 1, 0, 0, 0, 0, 2};

#pragma unroll
    for (int ts = 0; ts < NKSTEP; ++ts) {
        short8 am, as;
        if (D16[ts] == 2) {   // last step: odd position is k>=400 padding
            int a0 = qh ? zpad : (base + F0v[ts] * 48);
            am = *(const short8*)(lds + a0);
            as = *(const short8*)(lds + a0 + (qh ? 0 : SGOFF));
        } else {
            int ex = (D16[ts] ? qh768 : qh48) + F0v[ts] * 48;
            am = *(const short8*)(lds + base + ex);
            as = *(const short8*)(lds + SGOFF + base + ex);
        }
        short8 bm0 = Bmu8[(ts * 2 + 0) * 64 + l];
        short8 bm1 = Bmu8[(ts * 2 + 1) * 64 + l];
        short8 bs0 = Bsq8[(ts * 2 + 0) * 64 + l];
        short8 bs1 = Bsq8[(ts * 2 + 1) * 64 + l];

        accm[0] = __builtin_amdgcn_mfma_f32_16x16x32_bf16(am, bm0, accm[0], 0, 0, 0);
        accm[1] = __builtin_amdgcn_mfma_f32_16x16x32_bf16(am, bm1, accm[1], 0, 0, 0);
        accs[0] = __builtin_amdgcn_mfma_f32_16x16x32_bf16(as, bs0, accs[0], 0, 0, 0);
        accs[1] = __builtin_amdgcn_mfma_f32_16x16x32_bf16(as, bs1, accs[1], 0, 0, 0);
    }

    // ---- epilogue ----
    // C/D: row(pixel-col within tile) = q*4 + reg, col(channel) = l&15 (+16*half)
    const float spw0 = spw[col], spw1 = spw[16 + col];
    const int ho = ho0 + w;                    // always < HO (15*4+3 = 59)
#pragma unroll
    for (int reg = 0; reg < 4; ++reg) {
        int wo = wo0 + q * 4 + reg;
        if (wo >= WO) continue;
        float t12v = t12s[w * TW + q * 4 + reg];
        size_t basep = (((size_t)b * HO + ho) * WO + wo) * KN;
        __builtin_nontemporal_store(accm[0][reg], mu_out + basep + col);
        __builtin_nontemporal_store(accm[1][reg], mu_out + basep + 16 + col);
        float s0 = accs[0][reg] + t12v * spw0;
        float s1 = accs[1][reg] + t12v * spw1;
        __builtin_nontemporal_store(softplusf(s0), sig_out + basep + col);
        __builtin_nontemporal_store(softplusf(s1), sig_out + basep + 16 + col);
    }
}

extern "C" void kernel_launch(void* const* d_in, const int* in_sizes, int n_in,
                              void* d_out, int out_size, void* d_ws, size_t ws_size,
                              hipStream_t stream) {
    const float* mu_in   = (const float*)d_in[0];
    const float* sig_in  = (const float*)d_in[1];
    const float* w_mu    = (const float*)d_in[2];
    const float* w_sigma = (const float*)d_in[3];

    float* out     = (float*)d_out;
    float* mu_out  = out;
    float* sig_out = out + (size_t)OUT_PLANE;
    float* kl_out  = out + 2 * (size_t)OUT_PLANE;

    ushort* bmu = (ushort*)d_ws;                    // 13312 shorts
    ushort* bsq = bmu + 13312;                      // 13312 shorts
    float*  spw = (float*)(bsq + 13312);            // 32 floats

    prep_all<<<53, 256, 0, stream>>>(w_mu, w_sigma, bmu, bsq, spw, kl_out);
    vdp_main<<<dim3(4, 15, NB), 256, 0, stream>>>(mu_in, sig_in, bmu, bsq, spw,
                                                  mu_out, sig_out);
}

// Round 4
// 113.033 us; speedup vs baseline: 1.0630x; 1.0630x over previous
//
#include <hip/hip_runtime.h>
#include <hip/hip_bf16.h>
#include <math.h>

#define KK 5
#define KN 32
#define CIN 16
#define H 64
#define W 64
#define NB 32
#define HO 60
#define WO 60
#define D_TOT 400
#define OUT_PLANE (NB*HO*WO*KN)

// block tile: 8 out-rows x 16 out-cols, 4 waves, each wave 2 rows
#define TH 8
#define TW 16
#define IN_R 12      // TH + KK - 1
#define IN_C 20      // TW + KK - 1
#define CPAD 24      // c padded 16 -> 24 shorts (48B col stride: 2-way banks, free)
#define TILE_SH (IN_R*IN_C*CPAD)   // 5760 shorts per map
#define NKSTEP 13                  // ceil(400/32)

typedef short short8 __attribute__((ext_vector_type(8)));
typedef float f32x4 __attribute__((ext_vector_type(4)));

__device__ __forceinline__ ushort f2bf(float x) {
    __hip_bfloat16 h = __float2bfloat16(x);
    return *reinterpret_cast<ushort*>(&h);
}
__device__ __forceinline__ float bf2f(ushort u) {
    __hip_bfloat16 h = *reinterpret_cast<__hip_bfloat16*>(&u);
    return __bfloat162float(h);
}
__device__ __forceinline__ ushort4 pk4(float4 v) {
    union { __hip_bfloat162 h; ushort2 u; } a, b;
    a.h = __float22bfloat162_rn(make_float2(v.x, v.y));
    b.h = __float22bfloat162_rn(make_float2(v.z, v.w));
    ushort4 r;
    r.x = a.u.x; r.y = a.u.y; r.z = b.u.x; r.w = b.u.y;
    return r;
}
__device__ __forceinline__ float softplusf(float x) {
    return (x > 20.0f) ? x : __logf(1.0f + __expf(x));
}

// ---------------- prep: pack B fragments + spw + KL ----------------
// Bpack layout (short8 frags): idx8 = (t*2 + nt)*64 + lane ; element j:
//   k = t*32 + ((lane>>4)&3)*8 + j ; n = nt*16 + (lane&15); zero for k>=400
// Bsq'[k,n] = (w_mu[k,n]^2 + softplus(w_sigma[n])) / 400  (trace term folded in)
__global__ void prep_all(const float* __restrict__ w_mu, const float* __restrict__ w_sigma,
                         ushort* __restrict__ bmu, ushort* __restrict__ bsq,
                         float* __restrict__ spw, float* __restrict__ kl_out) {
    __shared__ float red[256];
    int t = threadIdx.x;
    if (blockIdx.x < 52) {
        int idx = blockIdx.x * 256 + t;     // < 13312
        int j  = idx & 7;
        int l  = (idx >> 3) & 63;
        int nt = (idx >> 9) & 1;
        int ts = idx >> 10;
        int k  = ts * 32 + ((l >> 4) & 3) * 8 + j;
        int n  = nt * 16 + (l & 15);
        if (k < D_TOT) {
            float w  = w_mu[k * KN + n];
            float sp = log1pf(expf(w_sigma[n]));
            bmu[idx] = f2bf(w);
            bsq[idx] = f2bf((w * w + sp) * (1.0f / 400.0f));
        } else {
            bmu[idx] = 0;
            bsq[idx] = 0;
        }
    } else {
        float s = 0.f;
        for (int i = t; i < D_TOT * KN; i += 256) { float w = w_mu[i]; s += w * w; }
        red[t] = s;
        __syncthreads();
        for (int off = 128; off > 0; off >>= 1) {
            if (t < off) red[t] += red[t + off];
            __syncthreads();
        }
        float sum_w2 = red[0];
        if (t < KN) {
            float ws = w_sigma[t];
            spw[t] = log1pf(expf(ws)) * (1.0f / 400.0f);
        }
        if (t == 0) {
            float sws = 0.f;
            for (int kn = 0; kn < KN; ++kn) {
                float ws = w_sigma[kn];
                float sp = log1pf(expf(ws));
                sws += -ws + sp * 100.0f;
            }
            float kl = 0.5f * (-4.605170186f - 1.0f + sws * (1.0f / 32.0f)
                               + sum_w2 * (100.0f / 12800.0f));
            *kl_out = kl;
        }
    }
}

// ---------------- main ----------------
__global__ __launch_bounds__(256, 4)
void vdp_main(const float* __restrict__ mu_in, const float* __restrict__ sig_in,
              const ushort* __restrict__ bmu_g, const ushort* __restrict__ bsq_g,
              const float* __restrict__ spw,
              float* __restrict__ mu_out, float* __restrict__ sig_out) {
    __shared__ ushort tiles[2 * TILE_SH + 8];
    __shared__ float csum[IN_R * IN_C];   // per input pixel: sum_c mu^2
    __shared__ float t12s[TH * TW];       // 5x5 window sums of csum

    const int b   = blockIdx.z;
    const int ho0 = blockIdx.y * TH;
    const int wo0 = blockIdx.x * TW;
    const int t   = threadIdx.x;

    if (t < 8) tiles[2 * TILE_SH + t] = 0;   // zero pad for k>=400 A reads

    // ---- stage 12x20x16 fp32 -> bf16 LDS (c-padded to 24) ----
    for (int i = t; i < IN_R * IN_C * 4; i += 256) {   // 960 float4 per map
        int row = i / 80;
        int rem = i - row * 80;
        int col = rem >> 2, c4 = rem & 3;
        int gh = ho0 + row, gw = wo0 + col;
        float4 vm = make_float4(0.f, 0.f, 0.f, 0.f), vs = vm;
        if (gh < H && gw < W) {
            size_t g = (((size_t)b * H + gh) * W + gw) * CIN + c4 * 4;
            vm = *(const float4*)(mu_in + g);
            vs = *(const float4*)(sig_in + g);
        }
        int sb = (row * IN_C + col) * CPAD + c4 * 4;
        *(ushort4*)&tiles[sb] = pk4(vm);
        *(ushort4*)&tiles[TILE_SH + sb] = pk4(vs);
    }
    __syncthreads();

    // ---- per-input-pixel channel sums: csum = sum_c mu^2 ----
    if (t < IN_R * IN_C) {
        int sb = t * CPAD;
        float acc = 0.f;
#pragma unroll
        for (int g = 0; g < 4; ++g) {
            ushort4 m4 = *(ushort4*)&tiles[sb + g * 4];
            float m0 = bf2f(m4.x), m1 = bf2f(m4.y), m2 = bf2f(m4.z), m3 = bf2f(m4.w);
            acc += m0 * m0 + m1 * m1 + m2 * m2 + m3 * m3;
        }
        csum[t] = acc;
    }
    __syncthreads();

    // ---- 5x5 window sums ----
    if (t < TH * TW) {
        int r = t >> 4, c = t & 15;
        float s = 0.f;
#pragma unroll
        for (int kh = 0; kh < KK; ++kh)
#pragma unroll
            for (int kw = 0; kw < KK; ++kw)
                s += csum[(r + kh) * IN_C + c + kw];
        t12s[t] = s;
    }
    __syncthreads();

    // ---- MFMA k-loop ----
    const int w    = t >> 6;
    const int l    = t & 63;
    const int col  = l & 15;
    const int q    = l >> 4;
    const int qh   = q >> 1;         // which (kh,kw) position within kstep pair
    const int qc   = q & 1;          // which c-half (0..7 / 8..15)

    const char* lds = (const char*)tiles;
    int base0 = ((2 * w + 0) * IN_C + col) * (CPAD * 2) + qc * 16;
    int base1 = ((2 * w + 1) * IN_C + col) * (CPAD * 2) + qc * 16;
    const int qh48  = qh * 48;
    const int qh768 = qh * 768;
    const int zpad  = 2 * TILE_SH * 2;   // byte offset of zero pad
    const int SGOFF = TILE_SH * 2;

    const short8* Bmu8 = (const short8*)bmu_g;
    const short8* Bsq8 = (const short8*)bsq_g;

    f32x4 accm[2][2], accs[2][2];
    f32x4 z = {0.f, 0.f, 0.f, 0.f};
#pragma unroll
    for (int a = 0; a < 2; ++a)
#pragma unroll
        for (int bn = 0; bn < 2; ++bn) { accm[a][bn] = z; accs[a][bn] = z; }

    // F0v = kh*20+kw spatial offset of even position; D16 flags row-crossing pairs
    constexpr int F0v[NKSTEP] = {0, 2, 4, 21, 23, 40, 42, 44, 61, 63, 80, 82, 84};
    constexpr int D16[NKSTEP] = {0, 0, 1, 0, 0, 0, 0, 1, 0, 0, 0, 0, 2};

#pragma unroll
    for (int ts = 0; ts < NKSTEP; ++ts) {
        short8 am0, am1, as0, as1;
        if (D16[ts] == 2) {  // last step: odd position is k>=400 padding
            int a0 = qh ? zpad : (base0 + F0v[ts] * 48);
            int a1 = qh ? zpad : (base1 + F0v[ts] * 48);
            am0 = *(const short8*)(lds + a0);
            am1 = *(const short8*)(lds + a1);
            as0 = *(const short8*)(lds + a0 + (qh ? 0 : SGOFF));
            as1 = *(const short8*)(lds + a1 + (qh ? 0 : SGOFF));
        } else {
            int ex = (D16[ts] ? qh768 : qh48) + F0v[ts] * 48;
            am0 = *(const short8*)(lds + base0 + ex);
            am1 = *(const short8*)(lds + base1 + ex);
            as0 = *(const short8*)(lds + SGOFF + base0 + ex);
            as1 = *(const short8*)(lds + SGOFF + base1 + ex);
        }
        short8 bm0 = Bmu8[(ts * 2 + 0) * 64 + l];
        short8 bm1 = Bmu8[(ts * 2 + 1) * 64 + l];
        short8 bs0 = Bsq8[(ts * 2 + 0) * 64 + l];
        short8 bs1 = Bsq8[(ts * 2 + 1) * 64 + l];

        accm[0][0] = __builtin_amdgcn_mfma_f32_16x16x32_bf16(am0, bm0, accm[0][0], 0, 0, 0);
        accm[0][1] = __builtin_amdgcn_mfma_f32_16x16x32_bf16(am0, bm1, accm[0][1], 0, 0, 0);
        accm[1][0] = __builtin_amdgcn_mfma_f32_16x16x32_bf16(am1, bm0, accm[1][0], 0, 0, 0);
        accm[1][1] = __builtin_amdgcn_mfma_f32_16x16x32_bf16(am1, bm1, accm[1][1], 0, 0, 0);
        accs[0][0] = __builtin_amdgcn_mfma_f32_16x16x32_bf16(as0, bs0, accs[0][0], 0, 0, 0);
        accs[0][1] = __builtin_amdgcn_mfma_f32_16x16x32_bf16(as0, bs1, accs[0][1], 0, 0, 0);
        accs[1][0] = __builtin_amdgcn_mfma_f32_16x16x32_bf16(as1, bs0, accs[1][0], 0, 0, 0);
        accs[1][1] = __builtin_amdgcn_mfma_f32_16x16x32_bf16(as1, bs1, accs[1][1], 0, 0, 0);
    }

    // ---- epilogue ----
    // C/D: row(pixel-col within tile) = q*4 + reg, col(channel) = l&15 (+16*nt)
    const float spw0 = spw[col], spw1 = spw[16 + col];
#pragma unroll
    for (int mt = 0; mt < 2; ++mt) {
        int ho = ho0 + 2 * w + mt;
        if (ho >= HO) continue;
#pragma unroll
        for (int reg = 0; reg < 4; ++reg) {
            int wo = wo0 + q * 4 + reg;
            if (wo >= WO) continue;
            float t12v = t12s[(2 * w + mt) * TW + q * 4 + reg];
            size_t basep = (((size_t)b * HO + ho) * WO + wo) * KN;
            mu_out[basep + col]      = accm[mt][0][reg];
            mu_out[basep + 16 + col] = accm[mt][1][reg];
            float s0 = accs[mt][0][reg] + t12v * spw0;
            float s1 = accs[mt][1][reg] + t12v * spw1;
            sig_out[basep + col]      = softplusf(s0);
            sig_out[basep + 16 + col] = softplusf(s1);
        }
    }
}

extern "C" void kernel_launch(void* const* d_in, const int* in_sizes, int n_in,
                              void* d_out, int out_size, void* d_ws, size_t ws_size,
                              hipStream_t stream) {
    const float* mu_in   = (const float*)d_in[0];
    const float* sig_in  = (const float*)d_in[1];
    const float* w_mu    = (const float*)d_in[2];
    const float* w_sigma = (const float*)d_in[3];

    float* out     = (float*)d_out;
    float* mu_out  = out;
    float* sig_out = out + (size_t)OUT_PLANE;
    float* kl_out  = out + 2 * (size_t)OUT_PLANE;

    ushort* bmu = (ushort*)d_ws;                    // 13312 shorts
    ushort* bsq = bmu + 13312;                      // 13312 shorts
    float*  spw = (float*)(bsq + 13312);            // 32 floats

    prep_all<<<53, 256, 0, stream>>>(w_mu, w_sigma, bmu, bsq, spw, kl_out);
    vdp_main<<<dim3(4, 8, NB), 256, 0, stream>>>(mu_in, sig_in, bmu, bsq, spw,
                                                 mu_out, sig_out);
}